// Round 1
// baseline (597.148 us; speedup 1.0000x reference)
//
#include <hip/hip_runtime.h>

#define NN 32
#define CC 256
#define LL 1024
#define IC 128
#define R2 9
#define DA 9216
#define DOUT 131072
#define EPSF 1e-5f

// ---------------- K1: q = x*wq^T, k = x*wk^T (1x1 convs) ----------------
// grid (16, 32): o-tile of 8 channels, n. block 256: thread = 4 pixels (float4)
__global__ __launch_bounds__(256) void k_qk(const float* __restrict__ x,
                                            const float* __restrict__ wq,
                                            const float* __restrict__ wk,
                                            float* __restrict__ q,
                                            float* __restrict__ k) {
  int n = blockIdx.y;
  int o0 = blockIdx.x * 8;
  int t = threadIdx.x;
  const float4* x4 = (const float4*)(x + (size_t)n * CC * LL);
  float4 qa[8], ka[8];
#pragma unroll
  for (int i = 0; i < 8; i++) {
    qa[i] = make_float4(0.f, 0.f, 0.f, 0.f);
    ka[i] = make_float4(0.f, 0.f, 0.f, 0.f);
  }
  for (int c = 0; c < CC; c++) {
    float4 xv = x4[c * (LL / 4) + t];
#pragma unroll
    for (int i = 0; i < 8; i++) {
      float wqv = wq[(o0 + i) * CC + c];
      float wkv = wk[(o0 + i) * CC + c];
      qa[i].x += xv.x * wqv; qa[i].y += xv.y * wqv;
      qa[i].z += xv.z * wqv; qa[i].w += xv.w * wqv;
      ka[i].x += xv.x * wkv; ka[i].y += xv.y * wkv;
      ka[i].z += xv.z * wkv; ka[i].w += xv.w * wkv;
    }
  }
#pragma unroll
  for (int i = 0; i < 8; i++) {
    size_t base = ((size_t)n * IC + (o0 + i)) * LL;
    *(float4*)(q + base + t * 4) = qa[i];
    *(float4*)(k + base + t * 4) = ka[i];
  }
}

// ---------------- K2: local 3x3 attention scores, f2 = 2 * (q . k_patch) ----
// grid (4, 32): l-tile 256, n. block 256: thread = 1 pixel.
__global__ __launch_bounds__(256) void k_attn(const float* __restrict__ q,
                                              const float* __restrict__ k,
                                              float* __restrict__ f2) {
  int n = blockIdx.y;
  int l = blockIdx.x * 256 + threadIdx.x;
  int h = l >> 5, w = l & 31;
  const float* qn = q + (size_t)n * IC * LL;
  const float* kn = k + (size_t)n * IC * LL;
  bool val[9];
  int off[9];
#pragma unroll
  for (int i = 0; i < 3; i++)
#pragma unroll
    for (int j = 0; j < 3; j++) {
      int r = i * 3 + j;
      int hh = h + i - 1, ww = w + j - 1;
      val[r] = (hh >= 0 && hh < 32 && ww >= 0 && ww < 32);
      off[r] = hh * 32 + ww;
    }
  float acc[9];
#pragma unroll
  for (int r = 0; r < 9; r++) acc[r] = 0.f;
  for (int c = 0; c < IC; c++) {
    float qv = qn[c * LL + l];
    const float* kc = kn + c * LL;
#pragma unroll
    for (int r = 0; r < 9; r++) {
      float kv = val[r] ? kc[off[r]] : 0.f;
      acc[r] += qv * kv;
    }
  }
#pragma unroll
  for (int r = 0; r < 9; r++) f2[(size_t)n * DA + r * LL + l] = 2.f * acc[r];
}

// ---------------- K3: LayerNorm over 9216, in place -------------------------
// grid 32 (n), block 256. Each thread holds its 36 elems in registers.
__global__ __launch_bounds__(256) void k_ln1(float* __restrict__ f2,
                                             const float* __restrict__ g1,
                                             const float* __restrict__ b1) {
  int n = blockIdx.x, t = threadIdx.x;
  float* row = f2 + (size_t)n * DA;
  float4 v[9];
  float s = 0.f, ss = 0.f;
#pragma unroll
  for (int kk = 0; kk < 9; kk++) {
    v[kk] = ((const float4*)row)[t + kk * 256];
    s += v[kk].x + v[kk].y + v[kk].z + v[kk].w;
    ss += v[kk].x * v[kk].x + v[kk].y * v[kk].y + v[kk].z * v[kk].z +
          v[kk].w * v[kk].w;
  }
#pragma unroll
  for (int o = 32; o; o >>= 1) {
    s += __shfl_down(s, o);
    ss += __shfl_down(ss, o);
  }
  __shared__ float ps[4], pss[4], stats[2];
  int wid = t >> 6, lid = t & 63;
  if (lid == 0) { ps[wid] = s; pss[wid] = ss; }
  __syncthreads();
  if (t == 0) {
    float S = ps[0] + ps[1] + ps[2] + ps[3];
    float SS = pss[0] + pss[1] + pss[2] + pss[3];
    float mu = S / DA;
    float var = SS / DA - mu * mu;
    stats[0] = mu;
    stats[1] = rsqrtf(var + EPSF);
  }
  __syncthreads();
  float mu = stats[0], rs = stats[1];
#pragma unroll
  for (int kk = 0; kk < 9; kk++) {
    float4 g = ((const float4*)g1)[t + kk * 256];
    float4 b = ((const float4*)b1)[t + kk * 256];
    float4 o;
    o.x = (v[kk].x - mu) * rs * g.x + b.x;
    o.y = (v[kk].y - mu) * rs * g.y + b.y;
    o.z = (v[kk].z - mu) * rs * g.z + b.z;
    o.w = (v[kk].w - mu) * rs * g.w + b.w;
    ((float4*)row)[t + kk * 256] = o;
  }
}

// ---------------- K4: h1 = relu(fln @ w1^T + b1)  [32,9216]x[256,9216] ------
// grid 256 (one o per block), block 256. acc[32 n] per thread; w1 row coalesced.
__global__ __launch_bounds__(256) void k_ffn1(const float* __restrict__ fln,
                                              const float* __restrict__ w1,
                                              const float* __restrict__ b1,
                                              float* __restrict__ h1) {
  int o = blockIdx.x, t = threadIdx.x;
  float acc[NN];
#pragma unroll
  for (int n = 0; n < NN; n++) acc[n] = 0.f;
  const float4* w1r = (const float4*)(w1 + (size_t)o * DA);
  for (int kk = 0; kk < 9; kk++) {
    float4 wv = w1r[t + kk * 256];
#pragma unroll
    for (int n = 0; n < NN; n++) {
      float4 fv = ((const float4*)(fln + (size_t)n * DA))[t + kk * 256];
      acc[n] += wv.x * fv.x + wv.y * fv.y + wv.z * fv.z + wv.w * fv.w;
    }
  }
#pragma unroll
  for (int n = 0; n < NN; n++)
#pragma unroll
    for (int s = 32; s; s >>= 1) acc[n] += __shfl_down(acc[n], s);
  __shared__ float part[4][NN];
  int wid = t >> 6, lid = t & 63;
  if (lid == 0) {
#pragma unroll
    for (int n = 0; n < NN; n++) part[wid][n] = acc[n];
  }
  __syncthreads();
  if (t < NN) {
    float sum = part[0][t] + part[1][t] + part[2][t] + part[3][t] + b1[o];
    h1[t * CC + o] = fmaxf(sum, 0.f);
  }
}

// ---------------- K5: h2 = h1 @ w2^T + b2  [32,256]x[131072,256] ------------
// grid 512 (j-tiles of 256), block 256. LDS: h1 transposed [c][n] + w2 chunk
// [cc][j]. Register tile 8n x 4j -> 32 FMA per 3 ds_read_b128.
__global__ __launch_bounds__(256) void k_ffn2(const float* __restrict__ h1,
                                              const float* __restrict__ w2,
                                              const float* __restrict__ b2,
                                              float* __restrict__ h2) {
  __shared__ float h1t[CC * 32];   // [c][n] 32KB
  __shared__ float wt[16 * 256];   // [cc][j] 16KB
  int t = threadIdx.x;
  int j0 = blockIdx.x * 256;
  for (int f = t; f < 32 * CC; f += 256) {
    int n = f & 31, c = f >> 5;
    h1t[c * 32 + n] = h1[n * CC + c];
  }
  int lane = t & 63, wid = t >> 6;
  int nb = wid * 8;
  int jj = lane * 4;
  float4 acc[8];
#pragma unroll
  for (int i = 0; i < 8; i++) acc[i] = make_float4(0.f, 0.f, 0.f, 0.f);

  for (int c0 = 0; c0 < CC; c0 += 16) {
    __syncthreads();
#pragma unroll
    for (int u = 0; u < 4; u++) {
      int f = t + u * 256;      // float4-unit index, 0..1023
      int jrow = f >> 2;
      int qq = f & 3;
      float4 wv = *(const float4*)(w2 + (size_t)(j0 + jrow) * CC + c0 + qq * 4);
      wt[(qq * 4 + 0) * 256 + jrow] = wv.x;
      wt[(qq * 4 + 1) * 256 + jrow] = wv.y;
      wt[(qq * 4 + 2) * 256 + jrow] = wv.z;
      wt[(qq * 4 + 3) * 256 + jrow] = wv.w;
    }
    __syncthreads();
#pragma unroll
    for (int cc = 0; cc < 16; cc++) {
      int c = c0 + cc;
      float4 ha = *(const float4*)&h1t[c * 32 + nb];
      float4 hb = *(const float4*)&h1t[c * 32 + nb + 4];
      float4 wv = *(const float4*)&wt[cc * 256 + jj];
#define FMA_ROW(hc, idx)                                                      \
  acc[idx].x += (hc) * wv.x; acc[idx].y += (hc) * wv.y;                       \
  acc[idx].z += (hc) * wv.z; acc[idx].w += (hc) * wv.w;
      FMA_ROW(ha.x, 0) FMA_ROW(ha.y, 1) FMA_ROW(ha.z, 2) FMA_ROW(ha.w, 3)
      FMA_ROW(hb.x, 4) FMA_ROW(hb.y, 5) FMA_ROW(hb.z, 6) FMA_ROW(hb.w, 7)
#undef FMA_ROW
    }
  }
  float4 bv = *(const float4*)(b2 + j0 + jj);
#pragma unroll
  for (int i = 0; i < 8; i++) {
    int n = nb + i;
    float4 o;
    o.x = acc[i].x + bv.x; o.y = acc[i].y + bv.y;
    o.z = acc[i].z + bv.z; o.w = acc[i].w + bv.w;
    *(float4*)(h2 + (size_t)n * DOUT + j0 + jj) = o;
  }
}

// ---------------- K6: LayerNorm stats over 131072 per n ---------------------
__global__ __launch_bounds__(1024) void k_ln2(const float* __restrict__ h2,
                                              float* __restrict__ st2) {
  int n = blockIdx.x, t = threadIdx.x;
  const float4* row = (const float4*)(h2 + (size_t)n * DOUT);
  float s = 0.f, ss = 0.f;
  for (int i = t; i < DOUT / 4; i += 1024) {
    float4 v = row[i];
    s += v.x + v.y + v.z + v.w;
    ss += v.x * v.x + v.y * v.y + v.z * v.z + v.w * v.w;
  }
#pragma unroll
  for (int o = 32; o; o >>= 1) {
    s += __shfl_down(s, o);
    ss += __shfl_down(ss, o);
  }
  __shared__ float ps[16], pss[16];
  int wid = t >> 6, lid = t & 63;
  if (lid == 0) { ps[wid] = s; pss[wid] = ss; }
  __syncthreads();
  if (t == 0) {
    float S = 0.f, SS = 0.f;
#pragma unroll
    for (int i = 0; i < 16; i++) { S += ps[i]; SS += pss[i]; }
    float mu = S / DOUT;
    float var = SS / DOUT - mu * mu;
    st2[n * 2] = mu;
    st2[n * 2 + 1] = rsqrtf(var + EPSF);
  }
}

// ---------------- K7: out = BN(y @ w_out^T) + x, y = LN2(h2)*g2+b2 ----------
// grid (4 l-tiles, 8 O-tiles, 32 n), block 256. LDS: w_out slice [o][Os] 16KB
// + normalized-y chunk [oc][l] 16KB. Register tile 8 O x 4 l.
__global__ __launch_bounds__(256) void k_out(
    const float* __restrict__ h2, const float* __restrict__ st2,
    const float* __restrict__ g2, const float* __restrict__ b2,
    const float* __restrict__ w_out, const float* __restrict__ bn_g,
    const float* __restrict__ bn_b, const float* __restrict__ bn_m,
    const float* __restrict__ bn_v, const float* __restrict__ x,
    float* __restrict__ out) {
  __shared__ float wt[IC * 32];    // [o][Os] 16KB
  __shared__ float yt[16 * 256];   // [oc][l] 16KB
  int t = threadIdx.x;
  int l0 = blockIdx.x * 256;
  int Ob = blockIdx.y * 32;
  int n = blockIdx.z;
  for (int f = t; f < IC * 32; f += 256) {
    int Os = f & 31, o = f >> 5;
    wt[o * 32 + Os] = w_out[(size_t)(Ob + Os) * IC + o];
  }
  float mu = st2[n * 2], rs = st2[n * 2 + 1];
  int lane = t & 63, wid = t >> 6;
  int Obase = wid * 8;
  int ll = lane * 4;
  float4 acc[8];
#pragma unroll
  for (int i = 0; i < 8; i++) acc[i] = make_float4(0.f, 0.f, 0.f, 0.f);

  for (int o0 = 0; o0 < IC; o0 += 16) {
    __syncthreads();
#pragma unroll
    for (int u = 0; u < 16; u++) {
      int d = (o0 + u) * LL + l0 + t;
      float yv = (h2[(size_t)n * DOUT + d] - mu) * rs * g2[d] + b2[d];
      yt[u * 256 + t] = yv;
    }
    __syncthreads();
#pragma unroll
    for (int oc = 0; oc < 16; oc++) {
      int o = o0 + oc;
      float4 w0 = *(const float4*)&wt[o * 32 + Obase];
      float4 w1v = *(const float4*)&wt[o * 32 + Obase + 4];
      float4 yv = *(const float4*)&yt[oc * 256 + ll];
#define FMA_O(wc, idx)                                                        \
  acc[idx].x += yv.x * (wc); acc[idx].y += yv.y * (wc);                       \
  acc[idx].z += yv.z * (wc); acc[idx].w += yv.w * (wc);
      FMA_O(w0.x, 0) FMA_O(w0.y, 1) FMA_O(w0.z, 2) FMA_O(w0.w, 3)
      FMA_O(w1v.x, 4) FMA_O(w1v.y, 5) FMA_O(w1v.z, 6) FMA_O(w1v.w, 7)
#undef FMA_O
    }
  }
#pragma unroll
  for (int i = 0; i < 8; i++) {
    int O = Ob + Obase + i;
    float sc = bn_g[O] * rsqrtf(bn_v[O] + EPSF);
    float sh = bn_b[O] - bn_m[O] * sc;
    size_t base = ((size_t)(n * CC + O)) * LL + l0 + ll;
    float4 xv = *(const float4*)(x + base);
    float4 r;
    r.x = acc[i].x * sc + sh + xv.x;
    r.y = acc[i].y * sc + sh + xv.y;
    r.z = acc[i].z * sc + sh + xv.z;
    r.w = acc[i].w * sc + sh + xv.w;
    *(float4*)(out + base) = r;
  }
}

extern "C" void kernel_launch(void* const* d_in, const int* in_sizes, int n_in,
                              void* d_out, int out_size, void* d_ws,
                              size_t ws_size, hipStream_t stream) {
  const float* x = (const float*)d_in[0];
  const float* wq = (const float*)d_in[1];
  const float* wk = (const float*)d_in[2];
  const float* gamma1 = (const float*)d_in[3];
  const float* beta1 = (const float*)d_in[4];
  const float* w1 = (const float*)d_in[5];
  const float* b1 = (const float*)d_in[6];
  const float* w2 = (const float*)d_in[7];
  const float* b2 = (const float*)d_in[8];
  const float* gamma2 = (const float*)d_in[9];
  const float* beta2 = (const float*)d_in[10];
  const float* w_out = (const float*)d_in[11];
  const float* bn_g = (const float*)d_in[12];
  const float* bn_b = (const float*)d_in[13];
  const float* bn_m = (const float*)d_in[14];
  const float* bn_v = (const float*)d_in[15];
  float* outp = (float*)d_out;
  float* ws = (float*)d_ws;

  // workspace layout (floats): q | k | f | h1 | stats2 ; h2 aliases q (dead)
  float* qb = ws;                   // 4194304
  float* kb = ws + 4194304;         // 4194304
  float* fb = ws + 8388608;         // 294912
  float* h1b = ws + 8683520;        // 8192
  float* st2 = ws + 8691712;        // 64
  float* h2b = qb;                  // reuse: q consumed by k_attn before k_ffn2

  if (ws_size < 8691776ull * sizeof(float)) return;  // fail visibly, no corrupt

  k_qk<<<dim3(16, 32), 256, 0, stream>>>(x, wq, wk, qb, kb);
  k_attn<<<dim3(4, 32), 256, 0, stream>>>(qb, kb, fb);
  k_ln1<<<dim3(32), 256, 0, stream>>>(fb, gamma1, beta1);
  k_ffn1<<<dim3(256), 256, 0, stream>>>(fb, w1, b1, h1b);
  k_ffn2<<<dim3(512), 256, 0, stream>>>(h1b, w2, b2, h2b);
  k_ln2<<<dim3(32), 1024, 0, stream>>>(h2b, st2);
  k_out<<<dim3(4, 8, 32), 256, 0, stream>>>(h2b, st2, gamma2, beta2, w_out,
                                            bn_g, bn_b, bn_m, bn_v, x, outp);
}

// Round 2
// 492.121 us; speedup vs baseline: 1.2134x; 1.2134x over previous
//
#include <hip/hip_runtime.h>

#define NN 32
#define CC 256
#define LL 1024
#define IC 128
#define R2 9
#define DA 9216
#define DOUT 131072
#define EPSF 1e-5f

// ---------------- K1: q = x*wq^T, k = x*wk^T (1x1 convs) ----------------
// grid (32 n, 32 o-tiles): blockIdx.x = n so XCD = n%8 (L2 locality for x).
// block 256: thread = 4 pixels (float4). Weights in LDS [c][o4] for
// ds_read_b128 broadcast; c-chunk of 8 gives 8 independent x loads per
// 256 FMAs.
__global__ __launch_bounds__(256) void k_qk(const float* __restrict__ x,
                                            const float* __restrict__ wq,
                                            const float* __restrict__ wk,
                                            float* __restrict__ q,
                                            float* __restrict__ k) {
  int n = blockIdx.x;
  int o0 = blockIdx.y * 4;
  int t = threadIdx.x;
  __shared__ float wqs[CC * 4], wks[CC * 4];
  for (int f = t; f < CC * 4; f += 256) {
    int i = f >> 8, c = f & 255;
    wqs[c * 4 + i] = wq[(size_t)(o0 + i) * CC + c];
    wks[c * 4 + i] = wk[(size_t)(o0 + i) * CC + c];
  }
  __syncthreads();
  const float4* x4 = (const float4*)(x + (size_t)n * CC * LL);
  float4 qa[4], ka[4];
#pragma unroll
  for (int i = 0; i < 4; i++) {
    qa[i] = make_float4(0.f, 0.f, 0.f, 0.f);
    ka[i] = make_float4(0.f, 0.f, 0.f, 0.f);
  }
  for (int c0 = 0; c0 < CC; c0 += 8) {
    float4 xv[8];
#pragma unroll
    for (int u = 0; u < 8; u++) xv[u] = x4[(c0 + u) * (LL / 4) + t];
#pragma unroll
    for (int u = 0; u < 8; u++) {
      int c = c0 + u;
      float4 wqv = *(const float4*)&wqs[c * 4];
      float4 wkv = *(const float4*)&wks[c * 4];
#define QK_FMA(wv, arr, comp)                                                 \
  arr[0].x += xv[u].x * wv.comp; arr[0].y += xv[u].y * wv.comp;               \
  arr[0].z += xv[u].z * wv.comp; arr[0].w += xv[u].w * wv.comp;
      // expand per output channel
      qa[0].x += xv[u].x * wqv.x; qa[0].y += xv[u].y * wqv.x;
      qa[0].z += xv[u].z * wqv.x; qa[0].w += xv[u].w * wqv.x;
      qa[1].x += xv[u].x * wqv.y; qa[1].y += xv[u].y * wqv.y;
      qa[1].z += xv[u].z * wqv.y; qa[1].w += xv[u].w * wqv.y;
      qa[2].x += xv[u].x * wqv.z; qa[2].y += xv[u].y * wqv.z;
      qa[2].z += xv[u].z * wqv.z; qa[2].w += xv[u].w * wqv.z;
      qa[3].x += xv[u].x * wqv.w; qa[3].y += xv[u].y * wqv.w;
      qa[3].z += xv[u].z * wqv.w; qa[3].w += xv[u].w * wqv.w;
      ka[0].x += xv[u].x * wkv.x; ka[0].y += xv[u].y * wkv.x;
      ka[0].z += xv[u].z * wkv.x; ka[0].w += xv[u].w * wkv.x;
      ka[1].x += xv[u].x * wkv.y; ka[1].y += xv[u].y * wkv.y;
      ka[1].z += xv[u].z * wkv.y; ka[1].w += xv[u].w * wkv.y;
      ka[2].x += xv[u].x * wkv.z; ka[2].y += xv[u].y * wkv.z;
      ka[2].z += xv[u].z * wkv.z; ka[2].w += xv[u].w * wkv.z;
      ka[3].x += xv[u].x * wkv.w; ka[3].y += xv[u].y * wkv.w;
      ka[3].z += xv[u].z * wkv.w; ka[3].w += xv[u].w * wkv.w;
#undef QK_FMA
    }
  }
#pragma unroll
  for (int i = 0; i < 4; i++) {
    size_t base = ((size_t)n * IC + (o0 + i)) * LL;
    *(float4*)(q + base + t * 4) = qa[i];
    *(float4*)(k + base + t * 4) = ka[i];
  }
}

// ---------------- K2: local 3x3 attention scores, f2 += 2*(q.k_patch) -------
// c-reduction split 4 ways, partials via atomicAdd into zeroed f2.
// grid (32 n, 4 c-splits, 4 l-tiles): n innermost so XCD = n%8.
__global__ __launch_bounds__(256) void k_attn(const float* __restrict__ q,
                                              const float* __restrict__ k,
                                              float* __restrict__ f2) {
  int n = blockIdx.x;
  int c0 = blockIdx.y * 32;
  int l = blockIdx.z * 256 + threadIdx.x;
  int h = l >> 5, w = l & 31;
  const float* qn = q + (size_t)n * IC * LL;
  const float* kn = k + (size_t)n * IC * LL;
  bool val[9];
  int off[9];
#pragma unroll
  for (int i = 0; i < 3; i++)
#pragma unroll
    for (int j = 0; j < 3; j++) {
      int r = i * 3 + j;
      int hh = h + i - 1, ww = w + j - 1;
      val[r] = (hh >= 0 && hh < 32 && ww >= 0 && ww < 32);
      off[r] = hh * 32 + ww;
    }
  float acc[9];
#pragma unroll
  for (int r = 0; r < 9; r++) acc[r] = 0.f;
#pragma unroll 4
  for (int cc = 0; cc < 32; cc++) {
    int c = c0 + cc;
    float qv = qn[c * LL + l];
    const float* kc = kn + c * LL;
#pragma unroll
    for (int r = 0; r < 9; r++) {
      float kv = val[r] ? kc[off[r]] : 0.f;
      acc[r] += qv * kv;
    }
  }
#pragma unroll
  for (int r = 0; r < 9; r++)
    atomicAdd(&f2[(size_t)n * DA + r * LL + l], 2.f * acc[r]);
}

// ---------------- K3: LayerNorm over 9216, in place -------------------------
__global__ __launch_bounds__(256) void k_ln1(float* __restrict__ f2,
                                             const float* __restrict__ g1,
                                             const float* __restrict__ b1) {
  int n = blockIdx.x, t = threadIdx.x;
  float* row = f2 + (size_t)n * DA;
  float4 v[9];
  float s = 0.f, ss = 0.f;
#pragma unroll
  for (int kk = 0; kk < 9; kk++) {
    v[kk] = ((const float4*)row)[t + kk * 256];
    s += v[kk].x + v[kk].y + v[kk].z + v[kk].w;
    ss += v[kk].x * v[kk].x + v[kk].y * v[kk].y + v[kk].z * v[kk].z +
          v[kk].w * v[kk].w;
  }
#pragma unroll
  for (int o = 32; o; o >>= 1) {
    s += __shfl_down(s, o);
    ss += __shfl_down(ss, o);
  }
  __shared__ float ps[4], pss[4], stats[2];
  int wid = t >> 6, lid = t & 63;
  if (lid == 0) { ps[wid] = s; pss[wid] = ss; }
  __syncthreads();
  if (t == 0) {
    float S = ps[0] + ps[1] + ps[2] + ps[3];
    float SS = pss[0] + pss[1] + pss[2] + pss[3];
    float mu = S / DA;
    float var = SS / DA - mu * mu;
    stats[0] = mu;
    stats[1] = rsqrtf(var + EPSF);
  }
  __syncthreads();
  float mu = stats[0], rs = stats[1];
#pragma unroll
  for (int kk = 0; kk < 9; kk++) {
    float4 g = ((const float4*)g1)[t + kk * 256];
    float4 b = ((const float4*)b1)[t + kk * 256];
    float4 o;
    o.x = (v[kk].x - mu) * rs * g.x + b.x;
    o.y = (v[kk].y - mu) * rs * g.y + b.y;
    o.z = (v[kk].z - mu) * rs * g.z + b.z;
    o.w = (v[kk].w - mu) * rs * g.w + b.w;
    ((float4*)row)[t + kk * 256] = o;
  }
}

// ---------------- K4: h1 = relu(fln @ w1^T + b1)  [32,9216]x[256,9216] ------
__global__ __launch_bounds__(256) void k_ffn1(const float* __restrict__ fln,
                                              const float* __restrict__ w1,
                                              const float* __restrict__ b1,
                                              float* __restrict__ h1) {
  int o = blockIdx.x, t = threadIdx.x;
  float acc[NN];
#pragma unroll
  for (int n = 0; n < NN; n++) acc[n] = 0.f;
  const float4* w1r = (const float4*)(w1 + (size_t)o * DA);
  for (int kk = 0; kk < 9; kk++) {
    float4 wv = w1r[t + kk * 256];
#pragma unroll
    for (int n = 0; n < NN; n++) {
      float4 fv = ((const float4*)(fln + (size_t)n * DA))[t + kk * 256];
      acc[n] += wv.x * fv.x + wv.y * fv.y + wv.z * fv.z + wv.w * fv.w;
    }
  }
#pragma unroll
  for (int n = 0; n < NN; n++)
#pragma unroll
    for (int s = 32; s; s >>= 1) acc[n] += __shfl_down(acc[n], s);
  __shared__ float part[4][NN];
  int wid = t >> 6, lid = t & 63;
  if (lid == 0) {
#pragma unroll
    for (int n = 0; n < NN; n++) part[wid][n] = acc[n];
  }
  __syncthreads();
  if (t < NN) {
    float sum = part[0][t] + part[1][t] + part[2][t] + part[3][t] + b1[o];
    h1[t * CC + o] = fmaxf(sum, 0.f);
  }
}

// ---------------- K5: h2 = h1 @ w2^T + b2  [32,256]x[131072,256] ------------
__global__ __launch_bounds__(256) void k_ffn2(const float* __restrict__ h1,
                                              const float* __restrict__ w2,
                                              const float* __restrict__ b2,
                                              float* __restrict__ h2) {
  __shared__ float h1t[CC * 32];   // [c][n] 32KB
  __shared__ float wt[16 * 256];   // [cc][j] 16KB
  int t = threadIdx.x;
  int j0 = blockIdx.x * 256;
  for (int f = t; f < 32 * CC; f += 256) {
    int n = f & 31, c = f >> 5;
    h1t[c * 32 + n] = h1[n * CC + c];
  }
  int lane = t & 63, wid = t >> 6;
  int nb = wid * 8;
  int jj = lane * 4;
  float4 acc[8];
#pragma unroll
  for (int i = 0; i < 8; i++) acc[i] = make_float4(0.f, 0.f, 0.f, 0.f);

  for (int c0 = 0; c0 < CC; c0 += 16) {
    __syncthreads();
#pragma unroll
    for (int u = 0; u < 4; u++) {
      int f = t + u * 256;      // float4-unit index, 0..1023
      int jrow = f >> 2;
      int qq = f & 3;
      float4 wv = *(const float4*)(w2 + (size_t)(j0 + jrow) * CC + c0 + qq * 4);
      wt[(qq * 4 + 0) * 256 + jrow] = wv.x;
      wt[(qq * 4 + 1) * 256 + jrow] = wv.y;
      wt[(qq * 4 + 2) * 256 + jrow] = wv.z;
      wt[(qq * 4 + 3) * 256 + jrow] = wv.w;
    }
    __syncthreads();
#pragma unroll
    for (int cc = 0; cc < 16; cc++) {
      int c = c0 + cc;
      float4 ha = *(const float4*)&h1t[c * 32 + nb];
      float4 hb = *(const float4*)&h1t[c * 32 + nb + 4];
      float4 wv = *(const float4*)&wt[cc * 256 + jj];
#define FMA_ROW(hc, idx)                                                      \
  acc[idx].x += (hc) * wv.x; acc[idx].y += (hc) * wv.y;                       \
  acc[idx].z += (hc) * wv.z; acc[idx].w += (hc) * wv.w;
      FMA_ROW(ha.x, 0) FMA_ROW(ha.y, 1) FMA_ROW(ha.z, 2) FMA_ROW(ha.w, 3)
      FMA_ROW(hb.x, 4) FMA_ROW(hb.y, 5) FMA_ROW(hb.z, 6) FMA_ROW(hb.w, 7)
#undef FMA_ROW
    }
  }
  float4 bv = *(const float4*)(b2 + j0 + jj);
#pragma unroll
  for (int i = 0; i < 8; i++) {
    int n = nb + i;
    float4 o;
    o.x = acc[i].x + bv.x; o.y = acc[i].y + bv.y;
    o.z = acc[i].z + bv.z; o.w = acc[i].w + bv.w;
    *(float4*)(h2 + (size_t)n * DOUT + j0 + jj) = o;
  }
}

// ---------------- K6: LayerNorm stats over 131072 per n ---------------------
__global__ __launch_bounds__(1024) void k_ln2(const float* __restrict__ h2,
                                              float* __restrict__ st2) {
  int n = blockIdx.x, t = threadIdx.x;
  const float4* row = (const float4*)(h2 + (size_t)n * DOUT);
  float s = 0.f, ss = 0.f;
  for (int i = t; i < DOUT / 4; i += 1024) {
    float4 v = row[i];
    s += v.x + v.y + v.z + v.w;
    ss += v.x * v.x + v.y * v.y + v.z * v.z + v.w * v.w;
  }
#pragma unroll
  for (int o = 32; o; o >>= 1) {
    s += __shfl_down(s, o);
    ss += __shfl_down(ss, o);
  }
  __shared__ float ps[16], pss[16];
  int wid = t >> 6, lid = t & 63;
  if (lid == 0) { ps[wid] = s; pss[wid] = ss; }
  __syncthreads();
  if (t == 0) {
    float S = 0.f, SS = 0.f;
#pragma unroll
    for (int i = 0; i < 16; i++) { S += ps[i]; SS += pss[i]; }
    float mu = S / DOUT;
    float var = SS / DOUT - mu * mu;
    st2[n * 2] = mu;
    st2[n * 2 + 1] = rsqrtf(var + EPSF);
  }
}

// ---------------- K7: out = BN(y @ w_out^T) + x, y = LN2(h2)*g2+b2 ----------
__global__ __launch_bounds__(256) void k_out(
    const float* __restrict__ h2, const float* __restrict__ st2,
    const float* __restrict__ g2, const float* __restrict__ b2,
    const float* __restrict__ w_out, const float* __restrict__ bn_g,
    const float* __restrict__ bn_b, const float* __restrict__ bn_m,
    const float* __restrict__ bn_v, const float* __restrict__ x,
    float* __restrict__ out) {
  __shared__ float wt[IC * 32];    // [o][Os] 16KB
  __shared__ float yt[16 * 256];   // [oc][l] 16KB
  int t = threadIdx.x;
  int l0 = blockIdx.x * 256;
  int Ob = blockIdx.y * 32;
  int n = blockIdx.z;
  for (int f = t; f < IC * 32; f += 256) {
    int Os = f & 31, o = f >> 5;
    wt[o * 32 + Os] = w_out[(size_t)(Ob + Os) * IC + o];
  }
  float mu = st2[n * 2], rs = st2[n * 2 + 1];
  int lane = t & 63, wid = t >> 6;
  int Obase = wid * 8;
  int ll = lane * 4;
  float4 acc[8];
#pragma unroll
  for (int i = 0; i < 8; i++) acc[i] = make_float4(0.f, 0.f, 0.f, 0.f);

  for (int o0 = 0; o0 < IC; o0 += 16) {
    __syncthreads();
#pragma unroll
    for (int u = 0; u < 16; u++) {
      int d = (o0 + u) * LL + l0 + t;
      float yv = (h2[(size_t)n * DOUT + d] - mu) * rs * g2[d] + b2[d];
      yt[u * 256 + t] = yv;
    }
    __syncthreads();
#pragma unroll
    for (int oc = 0; oc < 16; oc++) {
      int o = o0 + oc;
      float4 w0 = *(const float4*)&wt[o * 32 + Obase];
      float4 w1v = *(const float4*)&wt[o * 32 + Obase + 4];
      float4 yv = *(const float4*)&yt[oc * 256 + ll];
#define FMA_O(wc, idx)                                                        \
  acc[idx].x += yv.x * (wc); acc[idx].y += yv.y * (wc);                       \
  acc[idx].z += yv.z * (wc); acc[idx].w += yv.w * (wc);
      FMA_O(w0.x, 0) FMA_O(w0.y, 1) FMA_O(w0.z, 2) FMA_O(w0.w, 3)
      FMA_O(w1v.x, 4) FMA_O(w1v.y, 5) FMA_O(w1v.z, 6) FMA_O(w1v.w, 7)
#undef FMA_O
    }
  }
#pragma unroll
  for (int i = 0; i < 8; i++) {
    int O = Ob + Obase + i;
    float sc = bn_g[O] * rsqrtf(bn_v[O] + EPSF);
    float sh = bn_b[O] - bn_m[O] * sc;
    size_t base = ((size_t)(n * CC + O)) * LL + l0 + ll;
    float4 xv = *(const float4*)(x + base);
    float4 r;
    r.x = acc[i].x * sc + sh + xv.x;
    r.y = acc[i].y * sc + sh + xv.y;
    r.z = acc[i].z * sc + sh + xv.z;
    r.w = acc[i].w * sc + sh + xv.w;
    *(float4*)(out + base) = r;
  }
}

extern "C" void kernel_launch(void* const* d_in, const int* in_sizes, int n_in,
                              void* d_out, int out_size, void* d_ws,
                              size_t ws_size, hipStream_t stream) {
  const float* x = (const float*)d_in[0];
  const float* wq = (const float*)d_in[1];
  const float* wk = (const float*)d_in[2];
  const float* gamma1 = (const float*)d_in[3];
  const float* beta1 = (const float*)d_in[4];
  const float* w1 = (const float*)d_in[5];
  const float* b1 = (const float*)d_in[6];
  const float* w2 = (const float*)d_in[7];
  const float* b2 = (const float*)d_in[8];
  const float* gamma2 = (const float*)d_in[9];
  const float* beta2 = (const float*)d_in[10];
  const float* w_out = (const float*)d_in[11];
  const float* bn_g = (const float*)d_in[12];
  const float* bn_b = (const float*)d_in[13];
  const float* bn_m = (const float*)d_in[14];
  const float* bn_v = (const float*)d_in[15];
  float* outp = (float*)d_out;
  float* ws = (float*)d_ws;

  // workspace layout (floats): q | k | f | h1 | stats2 ; h2 aliases q (dead)
  float* qb = ws;                   // 4194304
  float* kb = ws + 4194304;         // 4194304
  float* fb = ws + 8388608;         // 294912
  float* h1b = ws + 8683520;        // 8192
  float* st2 = ws + 8691712;        // 64
  float* h2b = qb;                  // reuse: q consumed by k_attn before k_ffn2

  if (ws_size < 8691776ull * sizeof(float)) return;  // fail visibly, no corrupt

  hipMemsetAsync(fb, 0, (size_t)NN * DA * sizeof(float), stream);
  k_qk<<<dim3(32, 32), 256, 0, stream>>>(x, wq, wk, qb, kb);
  k_attn<<<dim3(32, 4, 4), 256, 0, stream>>>(qb, kb, fb);
  k_ln1<<<dim3(32), 256, 0, stream>>>(fb, gamma1, beta1);
  k_ffn1<<<dim3(256), 256, 0, stream>>>(fb, w1, b1, h1b);
  k_ffn2<<<dim3(512), 256, 0, stream>>>(h1b, w2, b2, h2b);
  k_ln2<<<dim3(32), 1024, 0, stream>>>(h2b, st2);
  k_out<<<dim3(4, 8, 32), 256, 0, stream>>>(h2b, st2, gamma2, beta2, w_out,
                                            bn_g, bn_b, bn_m, bn_v, x, outp);
}